// Round 1
// baseline (6810.742 us; speedup 1.0000x reference)
//
#include <hip/hip_runtime.h>
#include <hip/hip_bf16.h>
#include <math.h>

#define D_INNER 32
#define D_STATE 16
#define KDIRS 2
#define BATCH 2

// ---------------------------------------------------------------- bicubic
__device__ __forceinline__ float cubic_w(float d) {
    const float a = -0.75f;
    float d2 = d * d, d3 = d2 * d;
    if (d <= 1.0f) return (a + 2.0f) * d3 - (a + 3.0f) * d2 + 1.0f;
    if (d < 2.0f)  return a * d3 - 5.0f * a * d2 + 8.0f * a * d - 4.0f * a;
    return 0.0f;
}

__global__ void upsample_kernel(const float* __restrict__ in, float* __restrict__ out,
                                int h, int w, int H, int W, int total) {
    int i = blockIdx.x * 256 + threadIdx.x;
    if (i >= total) return;
    int ox = i % W; int t = i / W; int oy = t % H; int p = t / H; // p = b*32+d
    const float* ip = in + (size_t)p * h * w;
    float sy = (float)oy * ((float)(h - 1) / (float)(H - 1));
    float sx = (float)ox * ((float)(w - 1) / (float)(W - 1));
    int iy0 = (int)floorf(sy), ix0 = (int)floorf(sx);
    float wy[4], wx[4]; int yi[4], xi[4];
#pragma unroll
    for (int j = 0; j < 4; ++j) {
        int idy = iy0 + j - 1;
        wy[j] = cubic_w(fabsf(sy - (float)idy));
        yi[j] = min(max(idy, 0), h - 1);
        int idx = ix0 + j - 1;
        wx[j] = cubic_w(fabsf(sx - (float)idx));
        xi[j] = min(max(idx, 0), w - 1);
    }
    float acc = 0.f;
#pragma unroll
    for (int jy = 0; jy < 4; ++jy) {
        float rowv = 0.f;
#pragma unroll
        for (int jx = 0; jx < 4; ++jx)
            rowv += wx[jx] * ip[yi[jy] * w + xi[jx]];
        acc += wy[jy] * rowv;
    }
    out[(size_t)p * H * W + (size_t)oy * W + ox] = acc;
}

// ---------------------------------------------------------------- conv3x3
// Input channels come from two concatenated sources: s0 (c0 ch) then s1 (c1 ch).
// Output always 32 channels. Zero padding (1,1). Block = 16x16 output tile.
__global__ void conv3x3_kernel(const float* __restrict__ s0, int c0,
                               const float* __restrict__ s1, int c1,
                               const float* __restrict__ wgt, const float* __restrict__ bias,
                               float* __restrict__ out, int H, int W, int tilesX) {
    int b = blockIdx.z, oc = blockIdx.y;
    int ty = blockIdx.x / tilesX, tx = blockIdx.x % tilesX;
    int tid = threadIdx.x;
    int row = tid >> 4, col = tid & 15;
    int oy = ty * 16 + row, ox = tx * 16 + col;
    __shared__ float tileS[18][19];
    int Cin = c0 + c1;
    float acc = 0.f;
    const float* wbase = wgt + (size_t)oc * Cin * 9;
    for (int ic = 0; ic < Cin; ++ic) {
        const float* src = (ic < c0) ? (s0 + ((size_t)b * c0 + ic) * H * W)
                                     : (s1 + ((size_t)b * c1 + (ic - c0)) * H * W);
        for (int idx = tid; idx < 18 * 18; idx += 256) {
            int r = idx / 18, c = idx - r * 18;
            int gy = ty * 16 + r - 1, gx = tx * 16 + c - 1;
            tileS[r][c] = (gy >= 0 && gy < H && gx >= 0 && gx < W) ? src[(size_t)gy * W + gx] : 0.f;
        }
        __syncthreads();
        const float* wp = wbase + ic * 9;
        acc += tileS[row + 0][col + 0] * wp[0] + tileS[row + 0][col + 1] * wp[1] + tileS[row + 0][col + 2] * wp[2]
             + tileS[row + 1][col + 0] * wp[3] + tileS[row + 1][col + 1] * wp[4] + tileS[row + 1][col + 2] * wp[5]
             + tileS[row + 2][col + 0] * wp[6] + tileS[row + 2][col + 1] * wp[7] + tileS[row + 2][col + 2] * wp[8];
        __syncthreads();
    }
    if (oy < H && ox < W)
        out[((size_t)b * D_INNER + oc) * H * W + (size_t)oy * W + ox] = acc + bias[oc];
}

// ---------------------------------------------------------------- transpose (per 32x32 tile)
__global__ void transpose_kernel(const float* __restrict__ in, float* __restrict__ out,
                                 int H, int W) {
    __shared__ float t[32][33];
    int plane = blockIdx.y;
    int tilesX = W / 32;
    int tx = blockIdx.x % tilesX, ty = blockIdx.x / tilesX;
    const float* ip = in + (size_t)plane * H * W;
    float* op = out + (size_t)plane * H * W;
    int c = threadIdx.x & 31, r0 = threadIdx.x >> 5; // 32 cols x 8 rows
#pragma unroll
    for (int rr = 0; rr < 32; rr += 8) {
        int gy = ty * 32 + r0 + rr, gx = tx * 32 + c;
        t[r0 + rr][c] = ip[(size_t)gy * W + gx];
    }
    __syncthreads();
#pragma unroll
    for (int rr = 0; rr < 32; rr += 8) {
        int ow = tx * 32 + r0 + rr, oh = ty * 32 + c;   // out[w*H + h] = in[h*W + w]
        op[(size_t)ow * H + oh] = t[c][r0 + rr];
    }
}

// ---------------------------------------------------------------- projections (+softplus)
// x_dbl = xpw[k] @ xs ; dts = dtw[k] @ x_dbl[0:32]; delta = softplus(dts + bias)
__global__ void proj_kernel(const float* __restrict__ x, const float* __restrict__ xT,
                            const float* __restrict__ xpw, const float* __restrict__ dtw,
                            const float* __restrict__ dtb,
                            float* __restrict__ delta, float* __restrict__ Bm, float* __restrict__ Cm,
                            int L) {
    int k = blockIdx.y, b = blockIdx.z;
    int l = blockIdx.x * 256 + threadIdx.x;
    __shared__ float wxp[64 * 32];
    __shared__ float wdt[32 * 32];
    __shared__ float bdt[32];
    for (int idx = threadIdx.x; idx < 64 * 32; idx += 256) wxp[idx] = xpw[k * 2048 + idx];
    for (int idx = threadIdx.x; idx < 32 * 32; idx += 256) wdt[idx] = dtw[k * 1024 + idx];
    if (threadIdx.x < 32) bdt[threadIdx.x] = dtb[k * 32 + threadIdx.x];
    __syncthreads();
    const float* u = (k == 0 ? x : xT) + (size_t)b * D_INNER * L + l;
    float ud[32];
#pragma unroll
    for (int d = 0; d < 32; ++d) ud[d] = u[(size_t)d * L];
    float dts[32];
#pragma unroll
    for (int c = 0; c < 32; ++c) {
        float s = 0.f;
#pragma unroll
        for (int d = 0; d < 32; ++d) s += wxp[c * 32 + d] * ud[d];
        dts[c] = s;
    }
    size_t bkbase16 = (((size_t)b * KDIRS + k) * D_STATE) * L + l;
#pragma unroll
    for (int n = 0; n < 16; ++n) {
        float sB = 0.f, sC = 0.f;
#pragma unroll
        for (int d = 0; d < 32; ++d) {
            sB += wxp[(32 + n) * 32 + d] * ud[d];
            sC += wxp[(48 + n) * 32 + d] * ud[d];
        }
        Bm[bkbase16 + (size_t)n * L] = sB;
        Cm[bkbase16 + (size_t)n * L] = sC;
    }
    size_t bkbase32 = (((size_t)b * KDIRS + k) * D_INNER) * L + l;
#pragma unroll
    for (int d = 0; d < 32; ++d) {
        float s = bdt[d];
#pragma unroll
        for (int r = 0; r < 32; ++r) s += wdt[d * 32 + r] * dts[r];
        float sp = (s > 0.f) ? (s + log1pf(expf(-s))) : log1pf(expf(s));
        delta[bkbase32 + (size_t)d * L] = sp;
    }
}

// ---------------------------------------------------------------- selective scan
// 256 threads = 16 d-groups x 16 n. grid = B*K*2 = 8 blocks. Sequential over L.
// k=1 writes y at the row-major (transposed-back) position.
__global__ void scan_kernel(const float* __restrict__ x, const float* __restrict__ xT,
                            const float* __restrict__ delta, const float* __restrict__ Bm,
                            const float* __restrict__ Cm,
                            const float* __restrict__ A_logs, const float* __restrict__ Ds,
                            float* __restrict__ ys, int L, int H, int W) {
    int tid = threadIdx.x;
    int n = tid & 15, dloc = tid >> 4;
    int blk = blockIdx.x;
    int dbase = (blk & 1) * 16;
    int k = (blk >> 1) & 1;
    int b = blk >> 2;
    int d = dbase + dloc;
    const float* u  = (k == 0 ? x : xT) + ((size_t)b * D_INNER + d) * L;
    const float* dp = delta + (((size_t)b * KDIRS + k) * D_INNER + d) * L;
    const float* Bp = Bm + (((size_t)b * KDIRS + k) * D_STATE + n) * L;
    const float* Cp = Cm + (((size_t)b * KDIRS + k) * D_STATE + n) * L;
    float Aval = -expf(A_logs[(k * D_INNER + d) * D_STATE + n]);
    float Dval = Ds[k * D_INNER + d];
    float* yout = ys + (((size_t)b * KDIRS + k) * D_INNER + d) * L;
    float h = 0.f;
    int pos = 0, hc = 0;   // transposed-position counters for k=1
    for (int l4 = 0; l4 < L; l4 += 4) {
        float4 dv = *(const float4*)(dp + l4);
        float4 uv = *(const float4*)(u  + l4);
        float4 Bv = *(const float4*)(Bp + l4);
        float4 Cv = *(const float4*)(Cp + l4);
#pragma unroll
        for (int e = 0; e < 4; ++e) {
            float dl = e == 0 ? dv.x : e == 1 ? dv.y : e == 2 ? dv.z : dv.w;
            float ul = e == 0 ? uv.x : e == 1 ? uv.y : e == 2 ? uv.z : uv.w;
            float Bl = e == 0 ? Bv.x : e == 1 ? Bv.y : e == 2 ? Bv.z : Bv.w;
            float Cl = e == 0 ? Cv.x : e == 1 ? Cv.y : e == 2 ? Cv.z : Cv.w;
            float dA = expf(dl * Aval);
            h = fmaf(dA, h, dl * ul * Bl);
            float y = h * Cl;
            y += __shfl_xor(y, 1);
            y += __shfl_xor(y, 2);
            y += __shfl_xor(y, 4);
            y += __shfl_xor(y, 8);
            if (n == 0) {
                int outpos = (k == 0) ? (l4 + e) : pos;
                yout[outpos] = fmaf(Dval, ul, y);
            }
            pos += W;
            if (++hc == H) { hc = 0; pos += 1 - H * W; }
        }
    }
}

// ---------------------------------------------------------------- combine + LayerNorm(channel)
__global__ void combine_ln_kernel(const float* __restrict__ ys, const float* __restrict__ g,
                                  const float* __restrict__ beta, float* __restrict__ outp, int L) {
    int b = blockIdx.y;
    int l = blockIdx.x * 256 + threadIdx.x;
    const float* y0 = ys + ((size_t)b * KDIRS + 0) * D_INNER * L + l;
    const float* y1 = ys + ((size_t)b * KDIRS + 1) * D_INNER * L + l;
    float v[32]; float sum = 0.f;
#pragma unroll
    for (int d = 0; d < 32; ++d) {
        float t = y0[(size_t)d * L] + y1[(size_t)d * L];
        v[d] = t; sum += t;
    }
    float mu = sum * (1.0f / 32.0f);
    float var = 0.f;
#pragma unroll
    for (int d = 0; d < 32; ++d) { float t = v[d] - mu; var += t * t; }
    var *= (1.0f / 32.0f);
    float inv = 1.0f / sqrtf(var + 1e-5f);
#pragma unroll
    for (int d = 0; d < 32; ++d)
        outp[((size_t)b * D_INNER + d) * L + l] = (v[d] - mu) * inv * g[d] + beta[d];
}

// ---------------------------------------------------------------- host
extern "C" void kernel_launch(void* const* d_in, const int* in_sizes, int n_in,
                              void* d_out, int out_size, void* d_ws, size_t ws_size,
                              hipStream_t stream) {
    const float* out0 = (const float*)d_in[0];
    const float* out1 = (const float*)d_in[1];
    const float* out2 = (const float*)d_in[2];
    const float* out3 = (const float*)d_in[3];
    const float* cw[4] = {(const float*)d_in[4], (const float*)d_in[6],
                          (const float*)d_in[8], (const float*)d_in[10]};
    const float* cb[4] = {(const float*)d_in[5], (const float*)d_in[7],
                          (const float*)d_in[9], (const float*)d_in[11]};
    const float* xpw    = (const float*)d_in[12];
    const float* dtw    = (const float*)d_in[13];
    const float* dtb    = (const float*)d_in[14];
    const float* A_logs = (const float*)d_in[15];
    const float* Ds     = (const float*)d_in[16];
    const float* ln_g   = (const float*)d_in[17];
    const float* ln_b   = (const float*)d_in[18];

    // workspace layout (floats); MAXL = 128*128.
    // fus[1M] | x[1M] | xT[1M] | delta[2M] | Bm[1M] | Cm[1M] | ys[2M]  = 9M floats = 36 MB
    const size_t MAXL = 16384;
    float* ws    = (float*)d_ws;
    float* fus   = ws;
    float* xbuf  = fus   + (size_t)BATCH * 32 * MAXL;
    float* xTbuf = xbuf  + (size_t)BATCH * 32 * MAXL;
    float* delta = xTbuf + (size_t)BATCH * 32 * MAXL;
    float* Bm    = delta + (size_t)BATCH * KDIRS * 32 * MAXL;
    float* Cm    = Bm    + (size_t)BATCH * KDIRS * 16 * MAXL;
    float* ysbuf = Cm    + (size_t)BATCH * KDIRS * 16 * MAXL;
    float* up    = ysbuf; // alias: lifetimes disjoint (up dead before scan writes ys)

    // fusion = conv3x3(out3, conv0)  -> [2,32,16,16]
    conv3x3_kernel<<<dim3(1, 32, BATCH), 256, 0, stream>>>(
        out3, 768, nullptr, 0, cw[0], cb[0], fus, 16, 16, 1);

    struct Stage { int h, w, H, W, Cf; const float* feat; const float* w3; const float* b3; };
    Stage st[3] = {
        {16, 16,  32,  32, 384, out2, cw[1], cb[1]},
        {32, 32,  64,  64, 192, out1, cw[2], cb[2]},
        {64, 64, 128, 128,  96, out0, cw[3], cb[3]},
    };

    for (int i = 0; i < 3; ++i) {
        int h = st[i].h, w = st[i].w, H = st[i].H, W = st[i].W;
        int L = H * W;
        int total = BATCH * 32 * H * W;
        upsample_kernel<<<total / 256, 256, 0, stream>>>(fus, up, h, w, H, W, total);
        int tilesX = W / 16, tiles = (H / 16) * (W / 16);
        conv3x3_kernel<<<dim3(tiles, 32, BATCH), 256, 0, stream>>>(
            up, 32, st[i].feat, st[i].Cf, st[i].w3, st[i].b3, xbuf, H, W, tilesX);
        transpose_kernel<<<dim3((H / 32) * (W / 32), BATCH * 32), 256, 0, stream>>>(xbuf, xTbuf, H, W);
        proj_kernel<<<dim3(L / 256, KDIRS, BATCH), 256, 0, stream>>>(
            xbuf, xTbuf, xpw, dtw, dtb, delta, Bm, Cm, L);
        scan_kernel<<<8, 256, 0, stream>>>(xbuf, xTbuf, delta, Bm, Cm, A_logs, Ds, ysbuf, L, H, W);
        float* dst = (i == 2) ? (float*)d_out : fus;
        combine_ln_kernel<<<dim3(L / 256, BATCH), 256, 0, stream>>>(ysbuf, ln_g, ln_b, dst, L);
    }
}

// Round 2
// 1060.778 us; speedup vs baseline: 6.4205x; 6.4205x over previous
//
#include <hip/hip_runtime.h>
#include <hip/hip_bf16.h>
#include <math.h>

#define D_INNER 32
#define D_STATE 16
#define KDIRS 2
#define BATCH 2
#define IC_B 4

// ---------------------------------------------------------------- bicubic
__device__ __forceinline__ float cubic_w(float d) {
    const float a = -0.75f;
    float d2 = d * d, d3 = d2 * d;
    if (d <= 1.0f) return (a + 2.0f) * d3 - (a + 3.0f) * d2 + 1.0f;
    if (d < 2.0f)  return a * d3 - 5.0f * a * d2 + 8.0f * a * d - 4.0f * a;
    return 0.0f;
}

__global__ void upsample_kernel(const float* __restrict__ in, float* __restrict__ out,
                                int h, int w, int H, int W, int total) {
    int i = blockIdx.x * 256 + threadIdx.x;
    if (i >= total) return;
    int ox = i % W; int t = i / W; int oy = t % H; int p = t / H; // p = b*32+d
    const float* ip = in + (size_t)p * h * w;
    float sy = (float)oy * ((float)(h - 1) / (float)(H - 1));
    float sx = (float)ox * ((float)(w - 1) / (float)(W - 1));
    int iy0 = (int)floorf(sy), ix0 = (int)floorf(sx);
    float wy[4], wx[4]; int yi[4], xi[4];
#pragma unroll
    for (int j = 0; j < 4; ++j) {
        int idy = iy0 + j - 1;
        wy[j] = cubic_w(fabsf(sy - (float)idy));
        yi[j] = min(max(idy, 0), h - 1);
        int idx = ix0 + j - 1;
        wx[j] = cubic_w(fabsf(sx - (float)idx));
        xi[j] = min(max(idx, 0), w - 1);
    }
    float acc = 0.f;
#pragma unroll
    for (int jy = 0; jy < 4; ++jy) {
        float rowv = 0.f;
#pragma unroll
        for (int jx = 0; jx < 4; ++jx)
            rowv += wx[jx] * ip[yi[jy] * w + xi[jx]];
        acc += wy[jy] * rowv;
    }
    out[(size_t)p * H * W + (size_t)oy * W + ox] = acc;
}

// ---------------------------------------------------------------- conv3x3 (slice-parallel)
// Block computes ALL 32 output channels for one 16x16 tile over a 32-input-channel
// slice. Input channels concatenated: up (32 ch, if hasUp) then feat (cFeat ch).
// Partials written to partial[s][b][oc][HW]; reduced by conv_reduce_kernel.
__global__ void conv_partial_kernel(const float* __restrict__ up, const float* __restrict__ feat,
                                    int cFeat, int Cin, int hasUp,
                                    const float* __restrict__ wgt,
                                    float* __restrict__ partial,
                                    int H, int W, int tilesX) {
    int b = blockIdx.z, s = blockIdx.y;
    int ty = blockIdx.x / tilesX, tx = blockIdx.x % tilesX;
    int tid = threadIdx.x;
    int row = tid >> 4, col = tid & 15;
    __shared__ float tileS[IC_B][18][18];
    __shared__ float wsh[IC_B][32][9];
    float acc[32];
#pragma unroll
    for (int oc = 0; oc < 32; ++oc) acc[oc] = 0.f;
    int icg0 = s * 32;
    size_t HW = (size_t)H * W;
    for (int icb = 0; icb < 32; icb += IC_B) {
        for (int idx = tid; idx < IC_B * 324; idx += 256) {
            int ict = idx / 324, rem = idx - ict * 324;
            int r = rem / 18, cc = rem - r * 18;
            int icg = icg0 + icb + ict;
            const float* src = (hasUp && icg < 32)
                ? up + ((size_t)b * 32 + icg) * HW
                : feat + ((size_t)b * cFeat + (icg - (hasUp ? 32 : 0))) * HW;
            int gy = ty * 16 + r - 1, gx = tx * 16 + cc - 1;
            tileS[ict][r][cc] = (gy >= 0 && gy < H && gx >= 0 && gx < W) ? src[(size_t)gy * W + gx] : 0.f;
        }
        for (int idx = tid; idx < IC_B * 288; idx += 256) {
            int ict = idx / 288, rem = idx - ict * 288;
            int oc = rem / 9, t = rem - oc * 9;
            wsh[ict][oc][t] = wgt[((size_t)oc * Cin + icg0 + icb + ict) * 9 + t];
        }
        __syncthreads();
#pragma unroll
        for (int ict = 0; ict < IC_B; ++ict) {
            float t00 = tileS[ict][row + 0][col + 0], t01 = tileS[ict][row + 0][col + 1], t02 = tileS[ict][row + 0][col + 2];
            float t10 = tileS[ict][row + 1][col + 0], t11 = tileS[ict][row + 1][col + 1], t12 = tileS[ict][row + 1][col + 2];
            float t20 = tileS[ict][row + 2][col + 0], t21 = tileS[ict][row + 2][col + 1], t22 = tileS[ict][row + 2][col + 2];
#pragma unroll
            for (int oc = 0; oc < 32; ++oc) {
                const float* wp = wsh[ict][oc];
                acc[oc] += t00 * wp[0] + t01 * wp[1] + t02 * wp[2]
                         + t10 * wp[3] + t11 * wp[4] + t12 * wp[5]
                         + t20 * wp[6] + t21 * wp[7] + t22 * wp[8];
            }
        }
        __syncthreads();
    }
    int oy = ty * 16 + row, ox = tx * 16 + col;
    float* pp = partial + ((size_t)(s * gridDim.z + b) * 32) * HW + (size_t)oy * W + ox;
#pragma unroll
    for (int oc = 0; oc < 32; ++oc)
        pp[(size_t)oc * HW] = acc[oc];
}

__global__ void conv_reduce_kernel(const float* __restrict__ partial, const float* __restrict__ bias,
                                   float* __restrict__ out, int S, size_t planeTotal, int HW) {
    size_t i = (size_t)blockIdx.x * 256 + threadIdx.x;
    float s = bias[(i / (size_t)HW) & 31];
    for (int ss = 0; ss < S; ++ss) s += partial[(size_t)ss * planeTotal + i];
    out[i] = s;
}

// ---------------------------------------------------------------- transpose (per 32x32 tile)
__global__ void transpose_kernel(const float* __restrict__ in, float* __restrict__ out,
                                 int H, int W) {
    __shared__ float t[32][33];
    int plane = blockIdx.y;
    int tilesX = W / 32;
    int tx = blockIdx.x % tilesX, ty = blockIdx.x / tilesX;
    const float* ip = in + (size_t)plane * H * W;
    float* op = out + (size_t)plane * H * W;
    int c = threadIdx.x & 31, r0 = threadIdx.x >> 5;
#pragma unroll
    for (int rr = 0; rr < 32; rr += 8) {
        int gy = ty * 32 + r0 + rr, gx = tx * 32 + c;
        t[r0 + rr][c] = ip[(size_t)gy * W + gx];
    }
    __syncthreads();
#pragma unroll
    for (int rr = 0; rr < 32; rr += 8) {
        int ow = tx * 32 + r0 + rr, oh = ty * 32 + c;
        op[(size_t)ow * H + oh] = t[c][r0 + rr];
    }
}

// ---------------------------------------------------------------- projections (+softplus)
__global__ void proj_kernel(const float* __restrict__ x, const float* __restrict__ xT,
                            const float* __restrict__ xpw, const float* __restrict__ dtw,
                            const float* __restrict__ dtb,
                            float* __restrict__ delta, float* __restrict__ Bm, float* __restrict__ Cm,
                            int L) {
    int k = blockIdx.y, b = blockIdx.z;
    int l = blockIdx.x * 256 + threadIdx.x;
    __shared__ float wxp[64 * 32];
    __shared__ float wdt[32 * 32];
    __shared__ float bdt[32];
    for (int idx = threadIdx.x; idx < 64 * 32; idx += 256) wxp[idx] = xpw[k * 2048 + idx];
    for (int idx = threadIdx.x; idx < 32 * 32; idx += 256) wdt[idx] = dtw[k * 1024 + idx];
    if (threadIdx.x < 32) bdt[threadIdx.x] = dtb[k * 32 + threadIdx.x];
    __syncthreads();
    const float* u = (k == 0 ? x : xT) + (size_t)b * D_INNER * L + l;
    float ud[32];
#pragma unroll
    for (int d = 0; d < 32; ++d) ud[d] = u[(size_t)d * L];
    float dts[32];
#pragma unroll
    for (int c = 0; c < 32; ++c) {
        float s = 0.f;
#pragma unroll
        for (int d = 0; d < 32; ++d) s += wxp[c * 32 + d] * ud[d];
        dts[c] = s;
    }
    size_t bkbase16 = (((size_t)b * KDIRS + k) * D_STATE) * L + l;
#pragma unroll
    for (int n = 0; n < 16; ++n) {
        float sB = 0.f, sC = 0.f;
#pragma unroll
        for (int d = 0; d < 32; ++d) {
            sB += wxp[(32 + n) * 32 + d] * ud[d];
            sC += wxp[(48 + n) * 32 + d] * ud[d];
        }
        Bm[bkbase16 + (size_t)n * L] = sB;
        Cm[bkbase16 + (size_t)n * L] = sC;
    }
    size_t bkbase32 = (((size_t)b * KDIRS + k) * D_INNER) * L + l;
#pragma unroll
    for (int d = 0; d < 32; ++d) {
        float s = bdt[d];
#pragma unroll
        for (int r = 0; r < 32; ++r) s += wdt[d * 32 + r] * dts[r];
        float sp = (s > 0.f) ? (s + log1pf(expf(-s))) : log1pf(expf(s));
        delta[bkbase32 + (size_t)d * L] = sp;
    }
}

// ---------------------------------------------------------------- chunked selective scan
// Recurrence h_l = a_l h_{l-1} + b_l, a_l = exp(delta*A), b_l = delta*u*B.
// pass1: per chunk, P = prod(a), s = end state from h0=0.
// stitch: serial over C chunks -> chunk start states.
// pass2: re-scan each chunk from its start state, y = sum_n h*C (+ D*u).
// Block = 256 threads = 16 d x 16 n; grid (C, 8) with g = ((b*2+k)*2+dg).
__global__ void scan_pass1(const float* __restrict__ x, const float* __restrict__ xT,
                           const float* __restrict__ delta, const float* __restrict__ Bm,
                           const float* __restrict__ A_logs,
                           float* __restrict__ Ac, float* __restrict__ Sc, int L, int CL) {
    int tid = threadIdx.x, n = tid & 15, dloc = tid >> 4;
    int c = blockIdx.x, g = blockIdx.y;
    int dg = g & 1, k = (g >> 1) & 1, b = g >> 2;
    int d = dg * 16 + dloc;
    int l0 = c * CL;
    const float* u  = (k == 0 ? x : xT) + ((size_t)b * D_INNER + d) * L + l0;
    const float* dp = delta + (((size_t)b * KDIRS + k) * D_INNER + d) * L + l0;
    const float* Bp = Bm + (((size_t)b * KDIRS + k) * D_STATE + n) * L + l0;
    float Aval = -expf(A_logs[(k * D_INNER + d) * D_STATE + n]);
    float P = 1.f, s = 0.f;
    float4 dv = *(const float4*)dp;
    float4 uv = *(const float4*)u;
    float4 Bv = *(const float4*)Bp;
    for (int j = 0; j < CL; j += 4) {
        float4 dn, un, Bn;
        if (j + 4 < CL) {
            dn = *(const float4*)(dp + j + 4);
            un = *(const float4*)(u + j + 4);
            Bn = *(const float4*)(Bp + j + 4);
        }
#pragma unroll
        for (int e = 0; e < 4; ++e) {
            float dl = e == 0 ? dv.x : e == 1 ? dv.y : e == 2 ? dv.z : dv.w;
            float ul = e == 0 ? uv.x : e == 1 ? uv.y : e == 2 ? uv.z : uv.w;
            float Bl = e == 0 ? Bv.x : e == 1 ? Bv.y : e == 2 ? Bv.z : Bv.w;
            float a = expf(dl * Aval);
            s = fmaf(a, s, dl * ul * Bl);
            P *= a;
        }
        dv = dn; uv = un; Bv = Bn;
    }
    size_t o = ((size_t)c * 8 + g) * 256 + tid;
    Ac[o] = P;
    Sc[o] = s;
}

__global__ void scan_stitch(const float* __restrict__ Ac, const float* __restrict__ Sc,
                            float* __restrict__ Hs, int C) {
    int g = blockIdx.x, tid = threadIdx.x;
    size_t idx = (size_t)g * 256 + tid;
    float h = 0.f;
    for (int c = 0; c < C; ++c) {
        size_t o = (size_t)c * 2048 + idx;
        Hs[o] = h;
        h = fmaf(Ac[o], h, Sc[o]);
    }
}

__global__ void scan_pass2(const float* __restrict__ x, const float* __restrict__ xT,
                           const float* __restrict__ delta, const float* __restrict__ Bm,
                           const float* __restrict__ Cm,
                           const float* __restrict__ A_logs, const float* __restrict__ Ds,
                           const float* __restrict__ Hs,
                           float* __restrict__ ys, int L, int CL, int W, int hsh) {
    int tid = threadIdx.x, n = tid & 15, dloc = tid >> 4;
    int c = blockIdx.x, g = blockIdx.y;
    int dg = g & 1, k = (g >> 1) & 1, b = g >> 2;
    int d = dg * 16 + dloc;
    int l0 = c * CL;
    const float* u  = (k == 0 ? x : xT) + ((size_t)b * D_INNER + d) * L + l0;
    const float* dp = delta + (((size_t)b * KDIRS + k) * D_INNER + d) * L + l0;
    const float* Bp = Bm + (((size_t)b * KDIRS + k) * D_STATE + n) * L + l0;
    const float* Cp = Cm + (((size_t)b * KDIRS + k) * D_STATE + n) * L + l0;
    float Aval = -expf(A_logs[(k * D_INNER + d) * D_STATE + n]);
    float Dval = Ds[k * D_INNER + d];
    float* yout = ys + (((size_t)b * KDIRS + k) * D_INNER + d) * L;
    float h = Hs[((size_t)c * 8 + g) * 256 + tid];
    int Hdim = 1 << hsh;
    float4 dv = *(const float4*)dp;
    float4 uv = *(const float4*)u;
    float4 Bv = *(const float4*)Bp;
    float4 Cv = *(const float4*)Cp;
    for (int j = 0; j < CL; j += 4) {
        float4 dn, un, Bn, Cn;
        if (j + 4 < CL) {
            dn = *(const float4*)(dp + j + 4);
            un = *(const float4*)(u + j + 4);
            Bn = *(const float4*)(Bp + j + 4);
            Cn = *(const float4*)(Cp + j + 4);
        }
#pragma unroll
        for (int e = 0; e < 4; ++e) {
            float dl = e == 0 ? dv.x : e == 1 ? dv.y : e == 2 ? dv.z : dv.w;
            float ul = e == 0 ? uv.x : e == 1 ? uv.y : e == 2 ? uv.z : uv.w;
            float Bl = e == 0 ? Bv.x : e == 1 ? Bv.y : e == 2 ? Bv.z : Bv.w;
            float Cl = e == 0 ? Cv.x : e == 1 ? Cv.y : e == 2 ? Cv.z : Cv.w;
            float a = expf(dl * Aval);
            h = fmaf(a, h, dl * ul * Bl);
            float y = h * Cl;
            y += __shfl_xor(y, 1);
            y += __shfl_xor(y, 2);
            y += __shfl_xor(y, 4);
            y += __shfl_xor(y, 8);
            if (n == 0) {
                int l = l0 + j + e;
                int outpos;
                if (k == 0) outpos = l;
                else { int hh = l & (Hdim - 1); int wq = l >> hsh; outpos = hh * W + wq; }
                yout[outpos] = fmaf(Dval, ul, y);
            }
        }
        dv = dn; uv = un; Bv = Bn; Cv = Cn;
    }
}

// ---------------------------------------------------------------- combine + LayerNorm(channel)
__global__ void combine_ln_kernel(const float* __restrict__ ys, const float* __restrict__ g,
                                  const float* __restrict__ beta, float* __restrict__ outp, int L) {
    int b = blockIdx.y;
    int l = blockIdx.x * 256 + threadIdx.x;
    const float* y0 = ys + ((size_t)b * KDIRS + 0) * D_INNER * L + l;
    const float* y1 = ys + ((size_t)b * KDIRS + 1) * D_INNER * L + l;
    float v[32]; float sum = 0.f;
#pragma unroll
    for (int d = 0; d < 32; ++d) {
        float t = y0[(size_t)d * L] + y1[(size_t)d * L];
        v[d] = t; sum += t;
    }
    float mu = sum * (1.0f / 32.0f);
    float var = 0.f;
#pragma unroll
    for (int d = 0; d < 32; ++d) { float t = v[d] - mu; var += t * t; }
    var *= (1.0f / 32.0f);
    float inv = 1.0f / sqrtf(var + 1e-5f);
#pragma unroll
    for (int d = 0; d < 32; ++d)
        outp[((size_t)b * D_INNER + d) * L + l] = (v[d] - mu) * inv * g[d] + beta[d];
}

// ---------------------------------------------------------------- host
extern "C" void kernel_launch(void* const* d_in, const int* in_sizes, int n_in,
                              void* d_out, int out_size, void* d_ws, size_t ws_size,
                              hipStream_t stream) {
    const float* out0 = (const float*)d_in[0];
    const float* out1 = (const float*)d_in[1];
    const float* out2 = (const float*)d_in[2];
    const float* out3 = (const float*)d_in[3];
    const float* cw[4] = {(const float*)d_in[4], (const float*)d_in[6],
                          (const float*)d_in[8], (const float*)d_in[10]};
    const float* cb[4] = {(const float*)d_in[5], (const float*)d_in[7],
                          (const float*)d_in[9], (const float*)d_in[11]};
    const float* xpw    = (const float*)d_in[12];
    const float* dtw    = (const float*)d_in[13];
    const float* dtb    = (const float*)d_in[14];
    const float* A_logs = (const float*)d_in[15];
    const float* Ds     = (const float*)d_in[16];
    const float* ln_g   = (const float*)d_in[17];
    const float* ln_b   = (const float*)d_in[18];

    // workspace layout (floats); MAXL = 128*128. Total 9M floats = 36 MB.
    // fus[1M] | x[1M] | xT[1M] | delta[2M] | Bm[0.5M] | Cm[0.5M] | ys[2M]
    const size_t MAXL = 16384;
    float* ws    = (float*)d_ws;
    float* fus   = ws;
    float* xbuf  = fus   + (size_t)BATCH * 32 * MAXL;
    float* xTbuf = xbuf  + (size_t)BATCH * 32 * MAXL;
    float* delta = xTbuf + (size_t)BATCH * 32 * MAXL;
    float* Bm    = delta + (size_t)BATCH * KDIRS * 32 * MAXL;
    float* Cm    = Bm    + (size_t)BATCH * KDIRS * 16 * MAXL;
    float* ysbuf = Cm    + (size_t)BATCH * KDIRS * 16 * MAXL;
    float* up    = ysbuf;          // alias: up dead before scan writes ys
    float* partial = delta;        // alias: conv partials dead before proj writes delta/Bm/Cm (16 MB)
    // scan scratch aliases fus (dead between conv consumption and combine write): 1.5 MB max
    float* Ac = fus;
    float* Sc = fus + 64 * 2048;
    float* Hst = fus + 2 * 64 * 2048;

    // ---- fusion = conv3x3(out3, conv0) -> [2,32,16,16] (24 slices of 32 ic)
    {
        int S = 768 / 32;
        conv_partial_kernel<<<dim3(1, S, BATCH), 256, 0, stream>>>(
            nullptr, out3, 768, 768, 0, cw[0], partial, 16, 16, 1);
        size_t planeTotal = (size_t)BATCH * 32 * 256;
        conv_reduce_kernel<<<planeTotal / 256, 256, 0, stream>>>(
            partial, cb[0], fus, S, planeTotal, 256);
    }

    struct Stage { int h, w, H, W, Cf, CL, hsh; const float* feat; const float* w3; const float* b3; };
    Stage st[3] = {
        {16, 16,  32,  32, 384,  64, 5, out2, cw[1], cb[1]},
        {32, 32,  64,  64, 192, 128, 6, out1, cw[2], cb[2]},
        {64, 64, 128, 128,  96, 256, 7, out0, cw[3], cb[3]},
    };

    for (int i = 0; i < 3; ++i) {
        int H = st[i].H, W = st[i].W;
        int L = H * W;
        int h = st[i].h, w = st[i].w;
        int total = BATCH * 32 * H * W;
        upsample_kernel<<<total / 256, 256, 0, stream>>>(fus, up, h, w, H, W, total);

        int Cin = 32 + st[i].Cf;
        int S = Cin / 32;
        int tilesX = W / 16, tiles = (H / 16) * (W / 16);
        conv_partial_kernel<<<dim3(tiles, S, BATCH), 256, 0, stream>>>(
            up, st[i].feat, st[i].Cf, Cin, 1, st[i].w3, partial, H, W, tilesX);
        size_t planeTotal = (size_t)BATCH * 32 * L;
        conv_reduce_kernel<<<planeTotal / 256, 256, 0, stream>>>(
            partial, st[i].b3, xbuf, S, planeTotal, L);

        transpose_kernel<<<dim3((H / 32) * (W / 32), BATCH * 32), 256, 0, stream>>>(xbuf, xTbuf, H, W);
        proj_kernel<<<dim3(L / 256, KDIRS, BATCH), 256, 0, stream>>>(
            xbuf, xTbuf, xpw, dtw, dtb, delta, Bm, Cm, L);

        int CL = st[i].CL, C = L / CL;
        scan_pass1<<<dim3(C, 8), 256, 0, stream>>>(xbuf, xTbuf, delta, Bm, A_logs, Ac, Sc, L, CL);
        scan_stitch<<<8, 256, 0, stream>>>(Ac, Sc, Hst, C);
        scan_pass2<<<dim3(C, 8), 256, 0, stream>>>(xbuf, xTbuf, delta, Bm, Cm, A_logs, Ds, Hst,
                                                   ysbuf, L, CL, W, st[i].hsh);

        float* dst = (i == 2) ? (float*)d_out : fus;
        combine_ln_kernel<<<dim3(L / 256, BATCH), 256, 0, stream>>>(ysbuf, ln_g, ln_b, dst, L);
    }
}